// Round 8
// baseline (309.074 us; speedup 1.0000x reference)
//
#include <hip/hip_runtime.h>

// WindowAttention, MI355X gfx950 — round 8: bisection round.
// 2-kernel structure from R6/R7 (occupancy-first), but the per-head attention
// pipeline is ported VERBATIM from the R5 kernel that passed at 9.8e-4:
//   unswapped S = mfma(qa, kb); 16-lane softmax (xor 1/2/4/8); P quantized
//   UNNORMALIZED; o * rinv at store; SP=34 scratch layouts with lg==0 row-48.
// Kernel A: one wave per (window, head), x A-frags from global (f2bs, same bits
//   as R5's staged LDS), attn_out bf16 -> d_ws. Kernel B: proj streaming GEMM.

#define DIMC 192
#define NHEAD 6
#define HD 32
#define NTOK 49
#define NWIN 64
#define SCALE 0.17677669529663687f  // 1/sqrt(32)
#define SP 34                       // scratch pitch (shorts), R5-proven

typedef short bf16x8 __attribute__((ext_vector_type(8)));
typedef short bf16x4 __attribute__((ext_vector_type(4)));
typedef float f32x4 __attribute__((ext_vector_type(4)));

__device__ __forceinline__ short f2bs(float f) {
    // round-to-nearest-even fp32 -> bf16
    unsigned u = __builtin_bit_cast(unsigned, f);
    u = (u + 0x7fffu + ((u >> 16) & 1u)) >> 16;
    return (short)(unsigned short)u;
}

// 8-bf16 fragment load from LDS (two b64s)
__device__ __forceinline__ bf16x8 ld8(const short* p) {
    bf16x4 lo = *reinterpret_cast<const bf16x4*>(p);
    bf16x4 hi = *reinterpret_cast<const bf16x4*>(p + 4);
    return __builtin_shufflevector(lo, hi, 0, 1, 2, 3, 4, 5, 6, 7);
}

// 8 fp32 (two float4) -> bf16x8, RNE
__device__ __forceinline__ bf16x8 cvt8(const float4* p) {
    const float4 v0 = p[0], v1 = p[1];
    bf16x8 r;
    r[0] = f2bs(v0.x); r[1] = f2bs(v0.y); r[2] = f2bs(v0.z); r[3] = f2bs(v0.w);
    r[4] = f2bs(v1.x); r[5] = f2bs(v1.y); r[6] = f2bs(v1.z); r[7] = f2bs(v1.w);
    return r;
}

__global__ void prep_weights(const float* __restrict__ qkv_w,
                             const float* __restrict__ proj_w,
                             short* __restrict__ wT, short* __restrict__ pT) {
    int i = blockIdx.x * 256 + threadIdx.x;
    if (i < DIMC * 3 * DIMC) {  // qkv_w [192][576] -> wT [576][192] bf16
        int k = i / (3 * DIMC), c = i - k * (3 * DIMC);
        wT[c * DIMC + k] = f2bs(qkv_w[i]);
    }
    if (i < DIMC * DIMC) {      // proj_w [192][192] -> pT [192][192] bf16 (transposed)
        int k = i / DIMC, c = i - k * DIMC;
        pT[c * DIMC + k] = f2bs(proj_w[i]);
    }
}

// One QKV GEMM chunk (R5 logic, A-frags from GLOBAL x): 32 output cols, K=192.
// A rows: {lr, 16+lr, 32+lr, 48(clamped)}.
__device__ __forceinline__ void qkv_chunk_g(const float* __restrict__ xb,
                                            const short* __restrict__ wT,
                                            int c0, int lr, int lg,
                                            f32x4 (&acc)[4][2]) {
    #pragma unroll
    for (int m = 0; m < 4; ++m)
        #pragma unroll
        for (int n = 0; n < 2; ++n) acc[m][n] = f32x4{0.f, 0.f, 0.f, 0.f};
    __builtin_amdgcn_s_setprio(1);
    #pragma unroll
    for (int kk = 0; kk < 6; ++kk) {
        const int k0 = kk * 32 + lg * 8;
        bf16x8 a[4];
        #pragma unroll
        for (int m = 0; m < 4; ++m) {
            const int row = (m < 3) ? m * 16 + lr : 48;
            a[m] = cvt8(reinterpret_cast<const float4*>(&xb[row * DIMC + k0]));
        }
        #pragma unroll
        for (int n = 0; n < 2; ++n) {
            bf16x8 bw = *reinterpret_cast<const bf16x8*>(&wT[(c0 + n * 16 + lr) * DIMC + k0]);
            #pragma unroll
            for (int m = 0; m < 4; ++m)
                acc[m][n] = __builtin_amdgcn_mfma_f32_16x16x32_bf16(a[m], bw, acc[m][n], 0, 0, 0);
        }
    }
    __builtin_amdgcn_s_setprio(0);
}

// ---------------- Kernel A: QKV + attention, one wave per (window, head) ----
__global__ __launch_bounds__(64, 3)
void qkv_attn(const float* __restrict__ x, const float* __restrict__ mask,
              const float* __restrict__ qkv_b, const short* __restrict__ wT,
              short* __restrict__ attn)
{
    __shared__ short buf[1666];   // [49][34] scratch, sequentially reused (R5)
    // XCD swizzle (bijective: 12288 % 8 == 0)
    const int chunk = gridDim.x >> 3;
    const int logical = (blockIdx.x & 7) * chunk + (blockIdx.x >> 3);
    const int b = logical / NHEAD;
    const int h = logical - b * NHEAD;
    const int ln = threadIdx.x;
    const int lr = ln & 15, lg = ln >> 4;
    const float* xb = x + (long)b * NTOK * DIMC;

    bf16x8 qa[4], kb[4], vb[2][2];

    // ---------- QKV (3 chunks), transposes via buf — R5 verbatim ----------
    {
        f32x4 acc[4][2];
        // q -> buf [49][34] -> qa
        qkv_chunk_g(xb, wT, h * HD, lr, lg, acc);
        #pragma unroll
        for (int n2 = 0; n2 < 2; ++n2) {
            const float bias = qkv_b[h * HD + n2 * 16 + lr];
            #pragma unroll
            for (int m = 0; m < 3; ++m)
                #pragma unroll
                for (int r = 0; r < 4; ++r)
                    buf[(m * 16 + lg * 4 + r) * SP + n2 * 16 + lr] = f2bs(acc[m][n2][r] + bias);
            if (lg == 0) buf[48 * SP + n2 * 16 + lr] = f2bs(acc[3][n2][0] + bias);  // row 48
        }
        #pragma unroll
        for (int m = 0; m < 3; ++m)
            qa[m] = ld8(&buf[(m * 16 + lr) * SP + lg * 8]);
        qa[3] = ld8(&buf[48 * SP + lg * 8]);   // rows 48..63 -> token-48 copy (masked later)

        // k -> same buf -> kb
        qkv_chunk_g(xb, wT, DIMC + h * HD, lr, lg, acc);
        #pragma unroll
        for (int n2 = 0; n2 < 2; ++n2) {
            const float bias = qkv_b[DIMC + h * HD + n2 * 16 + lr];
            #pragma unroll
            for (int m = 0; m < 3; ++m)
                #pragma unroll
                for (int r = 0; r < 4; ++r)
                    buf[(m * 16 + lg * 4 + r) * SP + n2 * 16 + lr] = f2bs(acc[m][n2][r] + bias);
            if (lg == 0) buf[48 * SP + n2 * 16 + lr] = f2bs(acc[3][n2][0] + bias);
        }
        #pragma unroll
        for (int m = 0; m < 3; ++m)
            kb[m] = ld8(&buf[(m * 16 + lr) * SP + lg * 8]);
        kb[3] = ld8(&buf[48 * SP + lg * 8]);

        // v -> two sequential vT halves [32 d][34] (tokens 0..31, then 32..63)
        qkv_chunk_g(xb, wT, 2 * DIMC + h * HD, lr, lg, acc);
        #pragma unroll
        for (int half = 0; half < 2; ++half) {
            #pragma unroll
            for (int n2 = 0; n2 < 2; ++n2) {
                const float bias = qkv_b[2 * DIMC + h * HD + n2 * 16 + lr];
                #pragma unroll
                for (int mm = 0; mm < 2; ++mm) {
                    #pragma unroll
                    for (int r = 0; r < 4; ++r)
                        buf[(n2 * 16 + lr) * SP + mm * 16 + lg * 4 + r] =
                            f2bs(acc[half * 2 + mm][n2][r] + bias);  // pad tokens = finite copies
                }
            }
            #pragma unroll
            for (int nb = 0; nb < 2; ++nb)
                vb[half][nb] = ld8(&buf[(nb * 16 + lr) * SP + lg * 8]);
        }
    }

    // ---------- S = q k^T — R5 verbatim ----------
    f32x4 s[4][4];
    #pragma unroll
    for (int m = 0; m < 4; ++m)
        #pragma unroll
        for (int n = 0; n < 4; ++n) s[m][n] = f32x4{0.f, 0.f, 0.f, 0.f};
    __builtin_amdgcn_s_setprio(1);
    #pragma unroll
    for (int m = 0; m < 4; ++m)
        #pragma unroll
        for (int n = 0; n < 4; ++n)
            s[m][n] = __builtin_amdgcn_mfma_f32_16x16x32_bf16(qa[m], kb[n], s[m][n], 0, 0, 0);
    __builtin_amdgcn_s_setprio(0);

    // scale + mask + softmax WITHOUT max-subtraction — R5 verbatim
    const float* mrow = mask + (long)(b & (NWIN - 1)) * NTOK * NTOK;
    float rinv[4][4];
    #pragma unroll
    for (int m = 0; m < 4; ++m)
        #pragma unroll
        for (int n = 0; n < 4; ++n) {
            const int col = n * 16 + lr;
            #pragma unroll
            for (int r = 0; r < 4; ++r) {
                const int row = m * 16 + lg * 4 + r;
                float v = s[m][n][r];
                v = (row < NTOK && col < NTOK) ? v * SCALE + mrow[row * NTOK + col] : -1e30f;
                s[m][n][r] = __expf(v);
            }
        }
    #pragma unroll
    for (int m = 0; m < 4; ++m)
        #pragma unroll
        for (int r = 0; r < 4; ++r) {
            float sum = s[m][0][r] + s[m][1][r] + s[m][2][r] + s[m][3][r];
            sum += __shfl_xor(sum, 1);
            sum += __shfl_xor(sum, 2);
            sum += __shfl_xor(sum, 4);
            sum += __shfl_xor(sum, 8);
            rinv[m][r] = 1.f / sum;
        }

    // ---------- PV via two UNNORMALIZED P halves in buf — R5 verbatim ----------
    f32x4 o[4][2];
    #pragma unroll
    for (int m = 0; m < 4; ++m)
        #pragma unroll
        for (int n = 0; n < 2; ++n) o[m][n] = f32x4{0.f, 0.f, 0.f, 0.f};
    #pragma unroll
    for (int half = 0; half < 2; ++half) {
        #pragma unroll
        for (int m = 0; m < 3; ++m)
            #pragma unroll
            for (int n2 = 0; n2 < 2; ++n2)
                #pragma unroll
                for (int r = 0; r < 4; ++r)
                    buf[(m * 16 + lg * 4 + r) * SP + n2 * 16 + lr] = f2bs(s[m][half * 2 + n2][r]);
        if (lg == 0) {
            #pragma unroll
            for (int n2 = 0; n2 < 2; ++n2)
                buf[48 * SP + n2 * 16 + lr] = f2bs(s[3][half * 2 + n2][0]);
        }
        bf16x8 pa[4];
        #pragma unroll
        for (int mi = 0; mi < 3; ++mi)
            pa[mi] = ld8(&buf[(mi * 16 + lr) * SP + lg * 8]);
        pa[3] = ld8(&buf[48 * SP + lg * 8]);
        __builtin_amdgcn_s_setprio(1);
        #pragma unroll
        for (int nb = 0; nb < 2; ++nb)
            #pragma unroll
            for (int mi = 0; mi < 4; ++mi)
                o[mi][nb] = __builtin_amdgcn_mfma_f32_16x16x32_bf16(pa[mi], vb[half][nb], o[mi][nb], 0, 0, 0);
        __builtin_amdgcn_s_setprio(0);
    }

    // ---------- store attn_out = o * rinv (bf16) — R5 epilogue, to d_ws ------
    short* ab = attn + (long)b * NTOK * DIMC + h * HD;
    #pragma unroll
    for (int nb = 0; nb < 2; ++nb)
        #pragma unroll
        for (int m = 0; m < 4; ++m)
            #pragma unroll
            for (int r = 0; r < 4; ++r) {
                const int row = m * 16 + lg * 4 + r;
                if (row < NTOK)
                    ab[row * DIMC + nb * 16 + lr] = f2bs(o[m][nb][r] * rinv[m][r]);
            }
}

// ---------------- Kernel B: out = attn_out @ proj_w + proj_b ----------------
__global__ __launch_bounds__(256, 4)
void proj_gemm(const short* __restrict__ attn, const short* __restrict__ pT,
               const float* __restrict__ proj_b, float* __restrict__ out, long nrows)
{
    const int wv = threadIdx.x >> 6, ln = threadIdx.x & 63;
    const int lr = ln & 15, lg = ln >> 4;
    const long m0 = (long)blockIdx.x * 64;
    f32x4 acc[4][3];
    #pragma unroll
    for (int m = 0; m < 4; ++m)
        #pragma unroll
        for (int n = 0; n < 3; ++n) acc[m][n] = f32x4{0.f, 0.f, 0.f, 0.f};
    __builtin_amdgcn_s_setprio(1);
    #pragma unroll
    for (int kk = 0; kk < 6; ++kk) {
        const int k0 = kk * 32 + lg * 8;
        bf16x8 a[4];
        #pragma unroll
        for (int m = 0; m < 4; ++m) {
            long row = m0 + m * 16 + lr;
            if (row >= nrows) row = nrows - 1;
            a[m] = *reinterpret_cast<const bf16x8*>(&attn[row * DIMC + k0]);
        }
        #pragma unroll
        for (int n = 0; n < 3; ++n) {
            const int c = wv * 48 + n * 16 + lr;
            bf16x8 bw = *reinterpret_cast<const bf16x8*>(&pT[c * DIMC + k0]);
            #pragma unroll
            for (int m = 0; m < 4; ++m)
                acc[m][n] = __builtin_amdgcn_mfma_f32_16x16x32_bf16(a[m], bw, acc[m][n], 0, 0, 0);
        }
    }
    __builtin_amdgcn_s_setprio(0);
    #pragma unroll
    for (int n = 0; n < 3; ++n) {
        const int c = wv * 48 + n * 16 + lr;
        const float pb = proj_b[c];
        #pragma unroll
        for (int m = 0; m < 4; ++m)
            #pragma unroll
            for (int r = 0; r < 4; ++r) {
                const long row = m0 + m * 16 + lg * 4 + r;
                if (row < nrows) out[row * DIMC + c] = acc[m][n][r] + pb;
            }
    }
}

extern "C" void kernel_launch(void* const* d_in, const int* in_sizes, int n_in,
                              void* d_out, int out_size, void* d_ws, size_t ws_size,
                              hipStream_t stream) {
    const float* x      = (const float*)d_in[0];
    const float* mask   = (const float*)d_in[1];
    const float* qkv_w  = (const float*)d_in[2];
    const float* qkv_b  = (const float*)d_in[3];
    const float* proj_w = (const float*)d_in[4];
    const float* proj_b = (const float*)d_in[5];
    float* out = (float*)d_out;

    short* wT   = (short*)d_ws;                    // 576*192
    short* pT   = wT + DIMC * 3 * DIMC;            // 192*192
    short* attn = pT + DIMC * DIMC;                // nwin*49*192 bf16 (~38.5 MB)

    const int nwin = in_sizes[0] / (NTOK * DIMC);  // 2048
    const long nrows = (long)nwin * NTOK;          // 100352

    prep_weights<<<(DIMC * 3 * DIMC + 255) / 256, 256, 0, stream>>>(qkv_w, proj_w, wT, pT);
    qkv_attn<<<nwin * NHEAD, 64, 0, stream>>>(x, mask, qkv_b, wT, attn);
    proj_gemm<<<(int)((nrows + 63) / 64), 256, 0, stream>>>(attn, pT, proj_b, out, nrows);
}

// Round 9
// 222.479 us; speedup vs baseline: 1.3892x; 1.3892x over previous
//
#include <hip/hip_runtime.h>

// WindowAttention, MI355X gfx950 — round 9.
// R8's verified numerics, restructured for throughput:
//  - prep_x: x fp32 -> bf16 once (d_ws); removes 576 f2bs per wave from the hot loop.
//  - qkv_attn: 4 independent (window,head) waves per 256-thread block (no barriers);
//    per-wave LDS scratch [49][36] (8B-aligned rows). A-frags = direct bf16x8 loads.
//  - proj_gemm: streaming GEMM (unchanged).

#define DIMC 192
#define NHEAD 6
#define HD 32
#define NTOK 49
#define NWIN 64
#define SCALE 0.17677669529663687f  // 1/sqrt(32)
#define SP 36                       // scratch pitch (shorts): rows 72B -> 8B-aligned
#define WSZ (49 * SP)               // 1764 shorts per wave (3528 B, 8B-aligned)

typedef short bf16x8 __attribute__((ext_vector_type(8)));
typedef short bf16x4 __attribute__((ext_vector_type(4)));
typedef float f32x4 __attribute__((ext_vector_type(4)));

__device__ __forceinline__ short f2bs(float f) {
    // round-to-nearest-even fp32 -> bf16
    unsigned u = __builtin_bit_cast(unsigned, f);
    u = (u + 0x7fffu + ((u >> 16) & 1u)) >> 16;
    return (short)(unsigned short)u;
}

// 8-bf16 fragment load from 8B-aligned LDS
__device__ __forceinline__ bf16x8 ld8(const short* p) {
    bf16x4 lo = *reinterpret_cast<const bf16x4*>(p);
    bf16x4 hi = *reinterpret_cast<const bf16x4*>(p + 4);
    return __builtin_shufflevector(lo, hi, 0, 1, 2, 3, 4, 5, 6, 7);
}

// 8 fp32 (two float4) -> bf16x8, RNE
__device__ __forceinline__ bf16x8 cvt8(const float4* p) {
    const float4 v0 = p[0], v1 = p[1];
    bf16x8 r;
    r[0] = f2bs(v0.x); r[1] = f2bs(v0.y); r[2] = f2bs(v0.z); r[3] = f2bs(v0.w);
    r[4] = f2bs(v1.x); r[5] = f2bs(v1.y); r[6] = f2bs(v1.z); r[7] = f2bs(v1.w);
    return r;
}

__global__ void prep_weights(const float* __restrict__ qkv_w,
                             const float* __restrict__ proj_w,
                             short* __restrict__ wT, short* __restrict__ pT) {
    int i = blockIdx.x * 256 + threadIdx.x;
    if (i < DIMC * 3 * DIMC) {  // qkv_w [192][576] -> wT [576][192] bf16
        int k = i / (3 * DIMC), c = i - k * (3 * DIMC);
        wT[c * DIMC + k] = f2bs(qkv_w[i]);
    }
    if (i < DIMC * DIMC) {      // proj_w [192][192] -> pT [192][192] bf16 (transposed)
        int k = i / DIMC, c = i - k * DIMC;
        pT[c * DIMC + k] = f2bs(proj_w[i]);
    }
}

// x fp32 -> bf16, 8 elems/thread
__global__ __launch_bounds__(256)
void prep_x(const float* __restrict__ x, short* __restrict__ xbf, long n8) {
    long i = (long)blockIdx.x * 256 + threadIdx.x;
    if (i < n8)
        *reinterpret_cast<bf16x8*>(&xbf[i * 8]) =
            cvt8(reinterpret_cast<const float4*>(&x[i * 8]));
}

// One QKV GEMM chunk: 32 output cols (c0..c0+31), K=192. A-frags from bf16 x.
// A rows: {lr, 16+lr, 32+lr, 48(clamped)}.
__device__ __forceinline__ void qkv_chunk(const short* __restrict__ xb,
                                          const short* __restrict__ wT,
                                          int c0, int lr, int lg,
                                          f32x4 (&acc)[4][2]) {
    #pragma unroll
    for (int m = 0; m < 4; ++m)
        #pragma unroll
        for (int n = 0; n < 2; ++n) acc[m][n] = f32x4{0.f, 0.f, 0.f, 0.f};
    __builtin_amdgcn_s_setprio(1);
    #pragma unroll
    for (int kk = 0; kk < 6; ++kk) {
        const int k0 = kk * 32 + lg * 8;
        bf16x8 a[4];
        #pragma unroll
        for (int m = 0; m < 4; ++m) {
            const int row = (m < 3) ? m * 16 + lr : 48;
            a[m] = *reinterpret_cast<const bf16x8*>(&xb[row * DIMC + k0]);  // 16B-aligned
        }
        #pragma unroll
        for (int n = 0; n < 2; ++n) {
            bf16x8 bw = *reinterpret_cast<const bf16x8*>(&wT[(c0 + n * 16 + lr) * DIMC + k0]);
            #pragma unroll
            for (int m = 0; m < 4; ++m)
                acc[m][n] = __builtin_amdgcn_mfma_f32_16x16x32_bf16(a[m], bw, acc[m][n], 0, 0, 0);
        }
    }
    __builtin_amdgcn_s_setprio(0);
}

// ---------------- Kernel A: QKV + attention, 4 waves/block, 1 task/wave -----
__global__ __launch_bounds__(256, 4)
void qkv_attn(const short* __restrict__ xbf, const float* __restrict__ mask,
              const float* __restrict__ qkv_b, const short* __restrict__ wT,
              short* __restrict__ attn)
{
    __shared__ short smem[4 * WSZ];
    const int wv = threadIdx.x >> 6;
    const int ln = threadIdx.x & 63;
    const int lr = ln & 15, lg = ln >> 4;
    // XCD swizzle on blocks (3072 % 8 == 0 -> bijective)
    const int chunkB = gridDim.x >> 3;
    const int logical = (blockIdx.x & 7) * chunkB + (blockIdx.x >> 3);
    const int task = logical * 4 + wv;
    const int b = task / NHEAD;
    const int h = task - b * NHEAD;
    short* const buf = smem + wv * WSZ;
    const short* xb = xbf + (long)b * NTOK * DIMC;

    bf16x8 qa[4], kb[4], vb[2][2];

    // ---------- QKV (3 chunks), transposes via buf — R8/R5 numerics ----------
    {
        f32x4 acc[4][2];
        // q -> buf [49][36] -> qa
        qkv_chunk(xb, wT, h * HD, lr, lg, acc);
        #pragma unroll
        for (int n2 = 0; n2 < 2; ++n2) {
            const float bias = qkv_b[h * HD + n2 * 16 + lr];
            #pragma unroll
            for (int m = 0; m < 3; ++m)
                #pragma unroll
                for (int r = 0; r < 4; ++r)
                    buf[(m * 16 + lg * 4 + r) * SP + n2 * 16 + lr] = f2bs(acc[m][n2][r] + bias);
            if (lg == 0) buf[48 * SP + n2 * 16 + lr] = f2bs(acc[3][n2][0] + bias);  // row 48
        }
        #pragma unroll
        for (int m = 0; m < 3; ++m)
            qa[m] = ld8(&buf[(m * 16 + lr) * SP + lg * 8]);
        qa[3] = ld8(&buf[48 * SP + lg * 8]);   // rows 48..63 -> token-48 copy (masked later)

        // k -> same buf -> kb
        qkv_chunk(xb, wT, DIMC + h * HD, lr, lg, acc);
        #pragma unroll
        for (int n2 = 0; n2 < 2; ++n2) {
            const float bias = qkv_b[DIMC + h * HD + n2 * 16 + lr];
            #pragma unroll
            for (int m = 0; m < 3; ++m)
                #pragma unroll
                for (int r = 0; r < 4; ++r)
                    buf[(m * 16 + lg * 4 + r) * SP + n2 * 16 + lr] = f2bs(acc[m][n2][r] + bias);
            if (lg == 0) buf[48 * SP + n2 * 16 + lr] = f2bs(acc[3][n2][0] + bias);
        }
        #pragma unroll
        for (int m = 0; m < 3; ++m)
            kb[m] = ld8(&buf[(m * 16 + lr) * SP + lg * 8]);
        kb[3] = ld8(&buf[48 * SP + lg * 8]);

        // v -> two sequential vT halves [32 d][SP] (tokens 0..31, then 32..63)
        qkv_chunk(xb, wT, 2 * DIMC + h * HD, lr, lg, acc);
        #pragma unroll
        for (int half = 0; half < 2; ++half) {
            #pragma unroll
            for (int n2 = 0; n2 < 2; ++n2) {
                const float bias = qkv_b[2 * DIMC + h * HD + n2 * 16 + lr];
                #pragma unroll
                for (int mm = 0; mm < 2; ++mm) {
                    #pragma unroll
                    for (int r = 0; r < 4; ++r)
                        buf[(n2 * 16 + lr) * SP + mm * 16 + lg * 4 + r] =
                            f2bs(acc[half * 2 + mm][n2][r] + bias);  // pad tokens = finite copies
                }
            }
            #pragma unroll
            for (int nb = 0; nb < 2; ++nb)
                vb[half][nb] = ld8(&buf[(nb * 16 + lr) * SP + lg * 8]);
        }
    }

    // ---------- S = q k^T ----------
    f32x4 s[4][4];
    #pragma unroll
    for (int m = 0; m < 4; ++m)
        #pragma unroll
        for (int n = 0; n < 4; ++n) s[m][n] = f32x4{0.f, 0.f, 0.f, 0.f};
    __builtin_amdgcn_s_setprio(1);
    #pragma unroll
    for (int m = 0; m < 4; ++m)
        #pragma unroll
        for (int n = 0; n < 4; ++n)
            s[m][n] = __builtin_amdgcn_mfma_f32_16x16x32_bf16(qa[m], kb[n], s[m][n], 0, 0, 0);
    __builtin_amdgcn_s_setprio(0);

    // scale + mask + softmax WITHOUT max-subtraction (logits bounded)
    const float* mrow = mask + (long)(b & (NWIN - 1)) * NTOK * NTOK;
    float rinv[4][4];
    #pragma unroll
    for (int m = 0; m < 4; ++m)
        #pragma unroll
        for (int n = 0; n < 4; ++n) {
            const int col = n * 16 + lr;
            #pragma unroll
            for (int r = 0; r < 4; ++r) {
                const int row = m * 16 + lg * 4 + r;
                float v = s[m][n][r];
                v = (row < NTOK && col < NTOK) ? v * SCALE + mrow[row * NTOK + col] : -1e30f;
                s[m][n][r] = __expf(v);
            }
        }
    #pragma unroll
    for (int m = 0; m < 4; ++m)
        #pragma unroll
        for (int r = 0; r < 4; ++r) {
            float sum = s[m][0][r] + s[m][1][r] + s[m][2][r] + s[m][3][r];
            sum += __shfl_xor(sum, 1);
            sum += __shfl_xor(sum, 2);
            sum += __shfl_xor(sum, 4);
            sum += __shfl_xor(sum, 8);
            rinv[m][r] = 1.f / sum;
        }

    // ---------- PV via two UNNORMALIZED P halves in buf ----------
    f32x4 o[4][2];
    #pragma unroll
    for (int m = 0; m < 4; ++m)
        #pragma unroll
        for (int n = 0; n < 2; ++n) o[m][n] = f32x4{0.f, 0.f, 0.f, 0.f};
    #pragma unroll
    for (int half = 0; half < 2; ++half) {
        #pragma unroll
        for (int m = 0; m < 3; ++m)
            #pragma unroll
            for (int n2 = 0; n2 < 2; ++n2)
                #pragma unroll
                for (int r = 0; r < 4; ++r)
                    buf[(m * 16 + lg * 4 + r) * SP + n2 * 16 + lr] = f2bs(s[m][half * 2 + n2][r]);
        if (lg == 0) {
            #pragma unroll
            for (int n2 = 0; n2 < 2; ++n2)
                buf[48 * SP + n2 * 16 + lr] = f2bs(s[3][half * 2 + n2][0]);
        }
        bf16x8 pa[4];
        #pragma unroll
        for (int mi = 0; mi < 3; ++mi)
            pa[mi] = ld8(&buf[(mi * 16 + lr) * SP + lg * 8]);
        pa[3] = ld8(&buf[48 * SP + lg * 8]);
        __builtin_amdgcn_s_setprio(1);
        #pragma unroll
        for (int nb = 0; nb < 2; ++nb)
            #pragma unroll
            for (int mi = 0; mi < 4; ++mi)
                o[mi][nb] = __builtin_amdgcn_mfma_f32_16x16x32_bf16(pa[mi], vb[half][nb], o[mi][nb], 0, 0, 0);
        __builtin_amdgcn_s_setprio(0);
    }

    // ---------- store attn_out = o * rinv (bf16) -> d_ws ----------
    short* ab = attn + (long)b * NTOK * DIMC + h * HD;
    #pragma unroll
    for (int nb = 0; nb < 2; ++nb)
        #pragma unroll
        for (int m = 0; m < 4; ++m)
            #pragma unroll
            for (int r = 0; r < 4; ++r) {
                const int row = m * 16 + lg * 4 + r;
                if (row < NTOK)
                    ab[row * DIMC + nb * 16 + lr] = f2bs(o[m][nb][r] * rinv[m][r]);
            }
}

// ---------------- Kernel B: out = attn_out @ proj_w + proj_b ----------------
__global__ __launch_bounds__(256, 4)
void proj_gemm(const short* __restrict__ attn, const short* __restrict__ pT,
               const float* __restrict__ proj_b, float* __restrict__ out, long nrows)
{
    const int wv = threadIdx.x >> 6, ln = threadIdx.x & 63;
    const int lr = ln & 15, lg = ln >> 4;
    const long m0 = (long)blockIdx.x * 64;
    f32x4 acc[4][3];
    #pragma unroll
    for (int m = 0; m < 4; ++m)
        #pragma unroll
        for (int n = 0; n < 3; ++n) acc[m][n] = f32x4{0.f, 0.f, 0.f, 0.f};
    __builtin_amdgcn_s_setprio(1);
    #pragma unroll
    for (int kk = 0; kk < 6; ++kk) {
        const int k0 = kk * 32 + lg * 8;
        bf16x8 a[4];
        #pragma unroll
        for (int m = 0; m < 4; ++m) {
            long row = m0 + m * 16 + lr;
            if (row >= nrows) row = nrows - 1;
            a[m] = *reinterpret_cast<const bf16x8*>(&attn[row * DIMC + k0]);
        }
        #pragma unroll
        for (int n = 0; n < 3; ++n) {
            const int c = wv * 48 + n * 16 + lr;
            bf16x8 bw = *reinterpret_cast<const bf16x8*>(&pT[c * DIMC + k0]);
            #pragma unroll
            for (int m = 0; m < 4; ++m)
                acc[m][n] = __builtin_amdgcn_mfma_f32_16x16x32_bf16(a[m], bw, acc[m][n], 0, 0, 0);
        }
    }
    __builtin_amdgcn_s_setprio(0);
    #pragma unroll
    for (int n = 0; n < 3; ++n) {
        const int c = wv * 48 + n * 16 + lr;
        const float pb = proj_b[c];
        #pragma unroll
        for (int m = 0; m < 4; ++m)
            #pragma unroll
            for (int r = 0; r < 4; ++r) {
                const long row = m0 + m * 16 + lg * 4 + r;
                if (row < nrows) out[row * DIMC + c] = acc[m][n][r] + pb;
            }
    }
}

extern "C" void kernel_launch(void* const* d_in, const int* in_sizes, int n_in,
                              void* d_out, int out_size, void* d_ws, size_t ws_size,
                              hipStream_t stream) {
    const float* x      = (const float*)d_in[0];
    const float* mask   = (const float*)d_in[1];
    const float* qkv_w  = (const float*)d_in[2];
    const float* qkv_b  = (const float*)d_in[3];
    const float* proj_w = (const float*)d_in[4];
    const float* proj_b = (const float*)d_in[5];
    float* out = (float*)d_out;

    const int nwin = in_sizes[0] / (NTOK * DIMC);  // 2048
    const long nrows = (long)nwin * NTOK;          // 100352
    const long xelems = nrows * DIMC;              // 19,267,584

    short* wT   = (short*)d_ws;                    // 576*192
    short* pT   = wT + DIMC * 3 * DIMC;            // 192*192
    short* attn = pT + DIMC * DIMC;                // nrows*192 bf16 (~38.5 MB)
    short* xbf  = attn + xelems;                   // nrows*192 bf16 (~38.5 MB)

    prep_weights<<<(DIMC * 3 * DIMC + 255) / 256, 256, 0, stream>>>(qkv_w, proj_w, wT, pT);
    prep_x<<<(int)((xelems / 8 + 255) / 256), 256, 0, stream>>>(x, xbf, xelems / 8);
    qkv_attn<<<nwin * NHEAD / 4, 256, 0, stream>>>(xbf, mask, qkv_b, wT, attn);
    proj_gemm<<<(int)((nrows + 63) / 64), 256, 0, stream>>>(attn, pT, proj_b, out, nrows);
}